// Round 4
// baseline (236.496 us; speedup 1.0000x reference)
//
#include <hip/hip_runtime.h>
#include <math.h>

#define BATCH 2
#define DCH 64
#define PIX (512 * 512)
#define NSEG 641          // N_CLASSES*MAX_INDEX + 1
#define NCLS 5
#define IGNORE_LB 255
#define GCH 8             // channels per block in k_sums
#define NGRP (DCH / GCH)  // 8 channel groups
#define XCH 64            // pixel chunks in k_sums
#define TI 16             // pair-tile edge

// ---- workspace layout (bytes) ----
// zero region (memset each call):
#define OFF_M     0                                   // int m[BATCH]
#define OFF_PAIR  64                                  // float pairsum[BATCH][25]
#define OFF_CNT   320                                 // uint counts[BATCH][NSEG]
#define ZERO_BYTES 5504
// non-zeroed (fully rewritten each call):
#define OFF_SUM   ZERO_BYTES                          // float sums[BATCH][NSEG][DCH]
#define OFF_PART  (OFF_SUM + BATCH * NSEG * DCH * 4)  // float partials[BATCH][NGRP][XCH][GCH*NSEG]
#define OFF_KEYS  (OFF_PART + (size_t)BATCH * NGRP * XCH * GCH * NSEG * 4) // ushort keys

__global__ void k_max(const int* __restrict__ idx, int* __restrict__ mout) {
    const int b = blockIdx.y;
    const int4* p = (const int4*)(idx + (size_t)b * PIX);
    int v = 0;
    for (int i = blockIdx.x * blockDim.x + threadIdx.x; i < PIX / 4;
         i += gridDim.x * blockDim.x) {
        const int4 q = p[i];
        v = max(v, max(max(q.x, q.y), max(q.z, q.w)));
    }
    #pragma unroll
    for (int o = 32; o; o >>= 1) v = max(v, __shfl_down(v, o, 64));
    if ((threadIdx.x & 63) == 0) atomicMax(&mout[b], v);
}

__global__ void k_keys(const int* __restrict__ lab, const int* __restrict__ idx,
                       const int* __restrict__ mbuf,
                       unsigned short* __restrict__ keys,
                       unsigned int* __restrict__ counts) {
    __shared__ unsigned int hist[NSEG];
    const int b = blockIdx.y;
    for (int i = threadIdx.x; i < NSEG; i += blockDim.x) hist[i] = 0u;
    __syncthreads();
    const int m = mbuf[b];
    const int4* lb = (const int4*)(lab + (size_t)b * PIX);
    const int4* ib = (const int4*)(idx + (size_t)b * PIX);
    unsigned short* kb = keys + (size_t)b * PIX;
    for (int i = blockIdx.x * blockDim.x + threadIdx.x; i < PIX / 4;
         i += gridDim.x * blockDim.x) {
        const int4 l4 = lb[i];
        const int4 x4 = ib[i];
        int k[4];
        k[0] = (l4.x == IGNORE_LB) ? 0 : m * l4.x + x4.x;
        k[1] = (l4.y == IGNORE_LB) ? 0 : m * l4.y + x4.y;
        k[2] = (l4.z == IGNORE_LB) ? 0 : m * l4.z + x4.z;
        k[3] = (l4.w == IGNORE_LB) ? 0 : m * l4.w + x4.w;
        ushort4 o;
        o.x = (unsigned short)k[0]; o.y = (unsigned short)k[1];
        o.z = (unsigned short)k[2]; o.w = (unsigned short)k[3];
        *(ushort4*)(kb + 4 * i) = o;
        #pragma unroll
        for (int j = 0; j < 4; ++j) atomicAdd(&hist[k[j]], 1u);  // int: native ds_add_u32
    }
    __syncthreads();
    for (int i = threadIdx.x; i < NSEG; i += blockDim.x)
        if (hist[i]) atomicAdd(&counts[b * NSEG + i], hist[i]);
}

// Each block: 8 channels x 4096 pixels -> LDS table via ds_add_f32 -> partial dump.
__global__ __launch_bounds__(256) void k_sums(const float* __restrict__ feat,
                                              const unsigned short* __restrict__ keys,
                                              float* __restrict__ partials) {
    __shared__ float acc[GCH * NSEG];   // 20.5 KB
    const int b = blockIdx.z, grp = blockIdx.y, g0 = grp * GCH;
    for (int i = threadIdx.x; i < GCH * NSEG; i += blockDim.x) acc[i] = 0.f;
    __syncthreads();
    const int chunk = PIX / XCH;                   // 4096
    const int base = blockIdx.x * chunk;
    const unsigned short* kb = keys + (size_t)b * PIX + base;
    const float* fb = feat + ((size_t)b * DCH + g0) * PIX + base;
    for (int i = threadIdx.x * 4; i < chunk; i += blockDim.x * 4) {
        const ushort4 k4 = *(const ushort4*)(kb + i);
        float4 f[GCH];
        #pragma unroll
        for (int g = 0; g < GCH; ++g)
            f[g] = *(const float4*)(fb + (size_t)g * PIX + i);
        #pragma unroll
        for (int g = 0; g < GCH; ++g) {
            unsafeAtomicAdd(&acc[g * NSEG + k4.x], f[g].x);   // ds_add_f32, no CAS loop
            unsafeAtomicAdd(&acc[g * NSEG + k4.y], f[g].y);
            unsafeAtomicAdd(&acc[g * NSEG + k4.z], f[g].z);
            unsafeAtomicAdd(&acc[g * NSEG + k4.w], f[g].w);
        }
    }
    __syncthreads();
    float* dst = partials +
        (size_t)(((b * NGRP + grp) * XCH + blockIdx.x)) * (GCH * NSEG);
    for (int i = threadIdx.x; i < GCH * NSEG; i += blockDim.x) dst[i] = acc[i];
}

// Reduce XCH partials -> sums[b][s][d]. Coalesced reads along s.
__global__ void k_reduce(const float* __restrict__ partials,
                         float* __restrict__ sums) {
    const int t = blockIdx.x * blockDim.x + threadIdx.x;
    if (t >= BATCH * NGRP * GCH * NSEG) return;
    const int s = t % NSEG;
    int r = t / NSEG;
    const int g = r % GCH; r /= GCH;
    const int grp = r % NGRP;
    const int b = r / NGRP;
    const float* p = partials +
        (size_t)((b * NGRP + grp) * XCH) * (GCH * NSEG) + g * NSEG + s;
    float v = 0.f;
    #pragma unroll 4
    for (int x = 0; x < XCH; ++x) v += p[(size_t)x * (GCH * NSEG)];
    sums[((size_t)b * NSEG + s) * DCH + grp * GCH + g] = v;
}

// pairwise tile kernel: computes means on the fly from sums/counts
__global__ void k_pairs(const float* __restrict__ sums,
                        const unsigned int* __restrict__ counts,
                        const int* __restrict__ mbuf,
                        float* __restrict__ pairsum) {
    __shared__ float rI[TI][DCH + 1], rJ[TI][DCH + 1];  // +1 pad: kill bank conflict
    __shared__ int cI[TI], cJ[TI];
    __shared__ float ps[NCLS * NCLS];
    const int b = blockIdx.z;
    const int i0 = blockIdx.x * TI, j0 = blockIdx.y * TI;
    const int m = mbuf[b];
    if (threadIdx.x < NCLS * NCLS) ps[threadIdx.x] = 0.f;
    for (int t = threadIdx.x; t < TI * DCH; t += blockDim.x) {
        const int r = t >> 6, d = t & 63;
        const int si = i0 + r, sj = j0 + r;
        float vi = 0.f, vj = 0.f;
        if (si < NSEG) {
            const float c = fmaxf((float)counts[b * NSEG + si], 1.f);
            vi = sums[((size_t)b * NSEG + si) * DCH + d] / c;
        }
        if (sj < NSEG) {
            const float c = fmaxf((float)counts[b * NSEG + sj], 1.f);
            vj = sums[((size_t)b * NSEG + sj) * DCH + d] / c;
        }
        rI[r][d] = vi;
        rJ[r][d] = vj;
    }
    if (threadIdx.x < TI) {
        int si = i0 + threadIdx.x;
        bool ok = (si > 0 && si < NSEG && counts[b * NSEG + si] >= 2u);
        cI[threadIdx.x] = ok ? (si + m - 1) / m - 1 : -1;
        int sj = j0 + threadIdx.x;
        ok = (sj > 0 && sj < NSEG && counts[b * NSEG + sj] >= 2u);
        cJ[threadIdx.x] = ok ? (sj + m - 1) / m - 1 : -1;
    }
    __syncthreads();
    const int ti = threadIdx.x >> 4, tj = threadIdx.x & 15;
    const int ci = cI[ti], cj = cJ[tj];
    if (ci >= 0 && ci < NCLS && cj >= 0 && cj < NCLS) {
        float s = 0.f;
        #pragma unroll
        for (int d = 0; d < DCH; ++d) s += fabsf(rI[ti][d] - rJ[tj][d]);
        unsafeAtomicAdd(&ps[ci * NCLS + cj], s * (1.f / DCH));
    }
    __syncthreads();
    if (threadIdx.x < NCLS * NCLS && ps[threadIdx.x] != 0.f)
        unsafeAtomicAdd(&pairsum[b * NCLS * NCLS + threadIdx.x], ps[threadIdx.x]);
}

__global__ void k_final(const unsigned int* __restrict__ counts,
                        const float* __restrict__ pairsum,
                        const int* __restrict__ mbuf,
                        float* __restrict__ out) {
    __shared__ int nc[BATCH][NCLS];
    __shared__ float psl[BATCH * NCLS * NCLS];
    __shared__ int ml[BATCH];
    const int tid = threadIdx.x;
    if (tid < BATCH * NCLS) nc[tid / NCLS][tid % NCLS] = 0;
    if (tid < BATCH * NCLS * NCLS) psl[tid] = pairsum[tid];
    if (tid < BATCH) ml[tid] = mbuf[tid];
    __syncthreads();
    for (int t = tid; t < BATCH * NSEG; t += blockDim.x) {
        const int b = t / NSEG, s = t % NSEG;
        if (s > 0 && counts[t] >= 2u) {
            const int m = ml[b];
            const int c = (s + m - 1) / m - 1;
            if (c >= 0 && c < NCLS) atomicAdd(&nc[b][c], 1);
        }
    }
    __syncthreads();
    if (tid == 0) {
        float tot_s = 0.f, tot_c = 0.f;
        for (int b = 0; b < BATCH; ++b)
            for (int c1 = 0; c1 < NCLS; ++c1)
                for (int c2 = c1 + 1; c2 < NCLS; ++c2) {
                    const float np = (float)nc[b][c1] * (float)nc[b][c2];
                    if (np > 0.f) {
                        const float r = psl[b * NCLS * NCLS + c1 * NCLS + c2] / np;
                        tot_s += (r < 1.f) ? 0.5f * r * r : r - 0.5f;
                        tot_c += 1.f;
                    }
                }
        float mh = tot_s / fmaxf(tot_c, 1.f);
        mh = fmaxf(mh, 1e-12f);
        out[0] = (tot_c > 0.f) ? -logf(mh / (float)BATCH) : 0.f;
    }
}

extern "C" void kernel_launch(void* const* d_in, const int* in_sizes, int n_in,
                              void* d_out, int out_size, void* d_ws, size_t ws_size,
                              hipStream_t stream) {
    const float* feat = (const float*)d_in[0];
    const int* lab = (const int*)d_in[1];
    const int* idx = (const int*)d_in[2];
    float* out = (float*)d_out;
    char* ws = (char*)d_ws;

    int* mbuf            = (int*)(ws + OFF_M);
    float* pairsum       = (float*)(ws + OFF_PAIR);
    unsigned int* counts = (unsigned int*)(ws + OFF_CNT);
    float* sums          = (float*)(ws + OFF_SUM);
    float* partials      = (float*)(ws + OFF_PART);
    unsigned short* keys = (unsigned short*)(ws + OFF_KEYS);

    hipMemsetAsync(ws, 0, ZERO_BYTES, stream);
    k_max<<<dim3(32, BATCH), 256, 0, stream>>>(idx, mbuf);
    k_keys<<<dim3(64, BATCH), 256, 0, stream>>>(lab, idx, mbuf, keys, counts);
    k_sums<<<dim3(XCH, NGRP, BATCH), 256, 0, stream>>>(feat, keys, partials);
    {
        const int tot = BATCH * NGRP * GCH * NSEG;
        k_reduce<<<(tot + 255) / 256, 256, 0, stream>>>(partials, sums);
    }
    k_pairs<<<dim3((NSEG + TI - 1) / TI, (NSEG + TI - 1) / TI, BATCH), 256, 0, stream>>>(
        sums, counts, mbuf, pairsum);
    k_final<<<1, 256, 0, stream>>>(counts, pairsum, mbuf, out);
}

// Round 5
// 176.295 us; speedup vs baseline: 1.3415x; 1.3415x over previous
//
#include <hip/hip_runtime.h>
#include <math.h>

#define BATCH 2
#define DCH 64
#define PIX (512 * 512)
#define NCLS 5
#define IGNORE_LB 255
#define KSTR 129                      // fixed injective key stride (> MAX_INDEX)
#define NSEG 645                      // KSTR*4 + 128 + 1
#define TI 16                         // pair-tile edge

// ---- workspace layout (bytes) ----
// zero region (memset each call):
#define OFF_PAIR  0                                    // float pairsum[BATCH][25]
#define OFF_CNT   256                                  // uint counts[BATCH][NSEG]
#define OFF_SUM   5504                                 // float sums[BATCH][NSEG][DCH]
#define ZERO_BYTES 335744
// non-zeroed (fully rewritten each call):
#define OFF_CUR   335744                               // uint cursor[BATCH][NSEG]
#define OFF_KEYS  341248                               // ushort keys[BATCH][PIX]
#define OFF_SKEY  1389824                              // ushort skey[BATCH][PIX]  (key per sorted pos)
#define OFF_POS   2438400                              // uint posOf[BATCH][PIX]
#define OFF_FEATS 4535552                              // ushort(bf16) featS[BATCH][PIX][DCH]

__device__ __forceinline__ unsigned short f2bf(float f) {   // round-to-nearest-even
    unsigned int u = __float_as_uint(f);
    u += 0x7FFFu + ((u >> 16) & 1u);
    return (unsigned short)(u >> 16);
}

__global__ void k_keys(const int* __restrict__ lab, const int* __restrict__ idx,
                       unsigned short* __restrict__ keys,
                       unsigned int* __restrict__ counts) {
    __shared__ unsigned int hist[NSEG];
    const int b = blockIdx.y;
    for (int i = threadIdx.x; i < NSEG; i += blockDim.x) hist[i] = 0u;
    __syncthreads();
    const int4* lb = (const int4*)(lab + (size_t)b * PIX);
    const int4* ib = (const int4*)(idx + (size_t)b * PIX);
    unsigned short* kb = keys + (size_t)b * PIX;
    for (int i = blockIdx.x * blockDim.x + threadIdx.x; i < PIX / 4;
         i += gridDim.x * blockDim.x) {
        const int4 l4 = lb[i];
        const int4 x4 = ib[i];
        int k[4];
        k[0] = (l4.x == IGNORE_LB) ? 0 : KSTR * l4.x + x4.x;
        k[1] = (l4.y == IGNORE_LB) ? 0 : KSTR * l4.y + x4.y;
        k[2] = (l4.z == IGNORE_LB) ? 0 : KSTR * l4.z + x4.z;
        k[3] = (l4.w == IGNORE_LB) ? 0 : KSTR * l4.w + x4.w;
        ushort4 o;
        o.x = (unsigned short)k[0]; o.y = (unsigned short)k[1];
        o.z = (unsigned short)k[2]; o.w = (unsigned short)k[3];
        *(ushort4*)(kb + 4 * i) = o;
        #pragma unroll
        for (int j = 0; j < 4; ++j) atomicAdd(&hist[k[j]], 1u);
    }
    __syncthreads();
    for (int i = threadIdx.x; i < NSEG; i += blockDim.x)
        if (hist[i]) atomicAdd(&counts[b * NSEG + i], hist[i]);
}

// exclusive prefix sum of counts -> cursor. One wave per batch.
__global__ void k_scan(const unsigned int* __restrict__ counts,
                       unsigned int* __restrict__ cursor) {
    const int b = threadIdx.x >> 6, lane = threadIdx.x & 63;
    if (b >= BATCH) return;
    unsigned int carry = 0u;
    for (int c = 0; c < (NSEG + 63) / 64; ++c) {
        const int s = c * 64 + lane;
        unsigned int v0 = (s < NSEG) ? counts[b * NSEG + s] : 0u;
        unsigned int v = v0;
        #pragma unroll
        for (int o = 1; o < 64; o <<= 1) {
            unsigned int t = __shfl_up(v, o, 64);
            if (lane >= o) v += t;
        }
        if (s < NSEG) cursor[b * NSEG + s] = carry + (v - v0);
        carry += __shfl(v, 63, 64);
    }
}

// assign each pixel its sorted position (order within a key irrelevant)
__global__ void k_scatter(const unsigned short* __restrict__ keys,
                          unsigned int* __restrict__ cursor,
                          unsigned int* __restrict__ posOf,
                          unsigned short* __restrict__ skey) {
    const int b = blockIdx.y;
    const int base = blockIdx.x * 2048;
    const unsigned short* kb = keys + (size_t)b * PIX;
    unsigned int* po = posOf + (size_t)b * PIX;
    unsigned short* sk = skey + (size_t)b * PIX;
    #pragma unroll
    for (int j = 0; j < 8; ++j) {
        const int p = base + j * 256 + threadIdx.x;
        const int k = kb[p];
        const unsigned int pos = atomicAdd(&cursor[b * NSEG + k], 1u);
        po[p] = pos;
        sk[pos] = (unsigned short)k;
    }
}

// transpose [D][P] -> sorted [pos][D] with f32->bf16, 64x64 tiles via LDS
__global__ __launch_bounds__(256) void k_tpose(const float* __restrict__ feat,
                                               const unsigned int* __restrict__ posOf,
                                               unsigned short* __restrict__ featS) {
    __shared__ unsigned short tile[64][72];   // row stride 144B (16B-aligned), 9.2KB
    __shared__ unsigned int posLDS[64];
    const int b = blockIdx.y;
    const int P0 = blockIdx.x * 64;
    const int tid = threadIdx.x;
    if (tid < 64) posLDS[tid] = posOf[(size_t)b * PIX + P0 + tid];
    const float* fb = feat + (size_t)b * DCH * PIX;
    #pragma unroll
    for (int i = 0; i < 4; ++i) {
        const int idx = i * 256 + tid;
        const int ch = idx >> 4, px4 = idx & 15;
        const float4 v = *(const float4*)(fb + (size_t)ch * PIX + P0 + 4 * px4);
        tile[4 * px4 + 0][ch] = f2bf(v.x);
        tile[4 * px4 + 1][ch] = f2bf(v.y);
        tile[4 * px4 + 2][ch] = f2bf(v.z);
        tile[4 * px4 + 3][ch] = f2bf(v.w);
    }
    __syncthreads();
    unsigned short* fS = featS + (size_t)b * PIX * DCH;
    #pragma unroll
    for (int i = 0; i < 4; ++i) {
        const int idx = i * 256 + tid;
        const int px = idx >> 4, c4 = idx & 15;
        const unsigned int* t32 = (const unsigned int*)&tile[px][4 * c4];
        uint2 w; w.x = t32[0]; w.y = t32[1];
        *(uint2*)(fS + ((size_t)posLDS[px]) * DCH + 4 * c4) = w;
    }
}

// sorted segment sums: lane = channel, register accumulate, flush on key change
__global__ __launch_bounds__(256) void k_segsum(const unsigned short* __restrict__ featS,
                                                const unsigned short* __restrict__ skey,
                                                float* __restrict__ sums) {
    const int b = blockIdx.y;
    const int lane = threadIdx.x & 63, wid = threadIdx.x >> 6;
    const int q0 = (blockIdx.x * 4 + wid) * 64;
    const unsigned short* fS = featS + (size_t)b * PIX * DCH;
    const int sk = skey[(size_t)b * PIX + q0 + lane];
    int cur = __shfl(sk, 0, 64);
    float acc = 0.f;
    #pragma unroll 8
    for (int j = 0; j < 64; ++j) {
        const int k = __shfl(sk, j, 64);
        const unsigned int u = fS[(size_t)(q0 + j) * DCH + lane];
        const float f = __uint_as_float(u << 16);
        if (k != cur) {
            unsafeAtomicAdd(&sums[((size_t)b * NSEG + cur) * DCH + lane], acc);
            acc = 0.f;
            cur = k;
        }
        acc += f;
    }
    unsafeAtomicAdd(&sums[((size_t)b * NSEG + cur) * DCH + lane], acc);
}

// pairwise tile kernel: means on the fly from sums/counts
__global__ void k_pairs(const float* __restrict__ sums,
                        const unsigned int* __restrict__ counts,
                        float* __restrict__ pairsum) {
    __shared__ float rI[TI][DCH + 1], rJ[TI][DCH + 1];
    __shared__ int cI[TI], cJ[TI];
    __shared__ float ps[NCLS * NCLS];
    const int b = blockIdx.z;
    const int i0 = blockIdx.x * TI, j0 = blockIdx.y * TI;
    if (threadIdx.x < NCLS * NCLS) ps[threadIdx.x] = 0.f;
    for (int t = threadIdx.x; t < TI * DCH; t += blockDim.x) {
        const int r = t >> 6, d = t & 63;
        const int si = i0 + r, sj = j0 + r;
        float vi = 0.f, vj = 0.f;
        if (si < NSEG) {
            const float c = fmaxf((float)counts[b * NSEG + si], 1.f);
            vi = sums[((size_t)b * NSEG + si) * DCH + d] / c;
        }
        if (sj < NSEG) {
            const float c = fmaxf((float)counts[b * NSEG + sj], 1.f);
            vj = sums[((size_t)b * NSEG + sj) * DCH + d] / c;
        }
        rI[r][d] = vi;
        rJ[r][d] = vj;
    }
    if (threadIdx.x < TI) {
        int si = i0 + threadIdx.x;
        bool ok = (si > 0 && si < NSEG && counts[b * NSEG + si] >= 2u);
        cI[threadIdx.x] = ok ? (si - 1) / KSTR : -1;
        int sj = j0 + threadIdx.x;
        ok = (sj > 0 && sj < NSEG && counts[b * NSEG + sj] >= 2u);
        cJ[threadIdx.x] = ok ? (sj - 1) / KSTR : -1;
    }
    __syncthreads();
    const int ti = threadIdx.x >> 4, tj = threadIdx.x & 15;
    const int ci = cI[ti], cj = cJ[tj];
    if (ci >= 0 && ci < NCLS && cj >= 0 && cj < NCLS) {
        float s = 0.f;
        #pragma unroll
        for (int d = 0; d < DCH; ++d) s += fabsf(rI[ti][d] - rJ[tj][d]);
        unsafeAtomicAdd(&ps[ci * NCLS + cj], s * (1.f / DCH));
    }
    __syncthreads();
    if (threadIdx.x < NCLS * NCLS && ps[threadIdx.x] != 0.f)
        unsafeAtomicAdd(&pairsum[b * NCLS * NCLS + threadIdx.x], ps[threadIdx.x]);
}

__global__ void k_final(const unsigned int* __restrict__ counts,
                        const float* __restrict__ pairsum,
                        float* __restrict__ out) {
    __shared__ int nc[BATCH][NCLS];
    __shared__ float psl[BATCH * NCLS * NCLS];
    const int tid = threadIdx.x;
    if (tid < BATCH * NCLS) nc[tid / NCLS][tid % NCLS] = 0;
    if (tid < BATCH * NCLS * NCLS) psl[tid] = pairsum[tid];
    __syncthreads();
    for (int t = tid; t < BATCH * NSEG; t += blockDim.x) {
        const int b = t / NSEG, s = t % NSEG;
        if (s > 0 && counts[t] >= 2u) {
            const int c = (s - 1) / KSTR;
            if (c >= 0 && c < NCLS) atomicAdd(&nc[b][c], 1);
        }
    }
    __syncthreads();
    if (tid == 0) {
        float tot_s = 0.f, tot_c = 0.f;
        for (int b = 0; b < BATCH; ++b)
            for (int c1 = 0; c1 < NCLS; ++c1)
                for (int c2 = c1 + 1; c2 < NCLS; ++c2) {
                    const float np = (float)nc[b][c1] * (float)nc[b][c2];
                    if (np > 0.f) {
                        const float r = psl[b * NCLS * NCLS + c1 * NCLS + c2] / np;
                        tot_s += (r < 1.f) ? 0.5f * r * r : r - 0.5f;
                        tot_c += 1.f;
                    }
                }
        float mh = tot_s / fmaxf(tot_c, 1.f);
        mh = fmaxf(mh, 1e-12f);
        out[0] = (tot_c > 0.f) ? -logf(mh / (float)BATCH) : 0.f;
    }
}

extern "C" void kernel_launch(void* const* d_in, const int* in_sizes, int n_in,
                              void* d_out, int out_size, void* d_ws, size_t ws_size,
                              hipStream_t stream) {
    const float* feat = (const float*)d_in[0];
    const int* lab = (const int*)d_in[1];
    const int* idx = (const int*)d_in[2];
    float* out = (float*)d_out;
    char* ws = (char*)d_ws;

    float* pairsum       = (float*)(ws + OFF_PAIR);
    unsigned int* counts = (unsigned int*)(ws + OFF_CNT);
    float* sums          = (float*)(ws + OFF_SUM);
    unsigned int* cursor = (unsigned int*)(ws + OFF_CUR);
    unsigned short* keys = (unsigned short*)(ws + OFF_KEYS);
    unsigned short* skey = (unsigned short*)(ws + OFF_SKEY);
    unsigned int* posOf  = (unsigned int*)(ws + OFF_POS);
    unsigned short* featS= (unsigned short*)(ws + OFF_FEATS);

    hipMemsetAsync(ws, 0, ZERO_BYTES, stream);
    k_keys<<<dim3(64, BATCH), 256, 0, stream>>>(lab, idx, keys, counts);
    k_scan<<<1, 128, 0, stream>>>(counts, cursor);
    k_scatter<<<dim3(PIX / 2048, BATCH), 256, 0, stream>>>(keys, cursor, posOf, skey);
    k_tpose<<<dim3(PIX / 64, BATCH), 256, 0, stream>>>(feat, posOf, featS);
    k_segsum<<<dim3(PIX / 256, BATCH), 256, 0, stream>>>(featS, skey, sums);
    k_pairs<<<dim3((NSEG + TI - 1) / TI, (NSEG + TI - 1) / TI, BATCH), 256, 0, stream>>>(
        sums, counts, pairsum);
    k_final<<<1, 256, 0, stream>>>(counts, pairsum, out);
}

// Round 6
// 175.340 us; speedup vs baseline: 1.3488x; 1.0054x over previous
//
#include <hip/hip_runtime.h>
#include <math.h>

#define BATCH 2
#define DCH 64
#define PIX (512 * 512)
#define NCLS 5
#define IGNORE_LB 255
#define KSTR 129                      // fixed injective key stride (> MAX_INDEX)
#define NSEG 645                      // KSTR*4 + 128 + 1
#define TI 16                         // pair-tile edge

// ---- workspace layout (bytes) ----
// zero region (zeroed by k_zero each call):
#define OFF_PAIR  0                                    // float pairsum[BATCH][25]
#define OFF_CNT   256                                  // uint counts[BATCH][NSEG]
#define OFF_SUM   5504                                 // float sums[BATCH][NSEG][DCH]
#define ZERO_BYTES 335744                              // multiple of 16
// non-zeroed (fully rewritten each call):
#define OFF_CUR   335744                               // uint cursor[BATCH][NSEG]
#define OFF_KEYS  341248                               // ushort keys[BATCH][PIX]
#define OFF_SKEY  1389824                              // ushort skey[BATCH][PIX]  (key per sorted pos)
#define OFF_POS   2438400                              // uint posOf[BATCH][PIX]
#define OFF_FEATS 4535552                              // ushort(bf16) featS[BATCH][PIX][DCH]

__global__ void k_zero(float4* __restrict__ p) {
    const int n4 = ZERO_BYTES / 16;
    for (int i = blockIdx.x * blockDim.x + threadIdx.x; i < n4;
         i += gridDim.x * blockDim.x)
        p[i] = make_float4(0.f, 0.f, 0.f, 0.f);
}

__device__ __forceinline__ unsigned short f2bf(float f) {   // round-to-nearest-even
    unsigned int u = __float_as_uint(f);
    u += 0x7FFFu + ((u >> 16) & 1u);
    return (unsigned short)(u >> 16);
}

__global__ void k_keys(const int* __restrict__ lab, const int* __restrict__ idx,
                       unsigned short* __restrict__ keys,
                       unsigned int* __restrict__ counts) {
    __shared__ unsigned int hist[NSEG];
    const int b = blockIdx.y;
    for (int i = threadIdx.x; i < NSEG; i += blockDim.x) hist[i] = 0u;
    __syncthreads();
    const int4* lb = (const int4*)(lab + (size_t)b * PIX);
    const int4* ib = (const int4*)(idx + (size_t)b * PIX);
    unsigned short* kb = keys + (size_t)b * PIX;
    for (int i = blockIdx.x * blockDim.x + threadIdx.x; i < PIX / 4;
         i += gridDim.x * blockDim.x) {
        const int4 l4 = lb[i];
        const int4 x4 = ib[i];
        int k[4];
        k[0] = (l4.x == IGNORE_LB) ? 0 : KSTR * l4.x + x4.x;
        k[1] = (l4.y == IGNORE_LB) ? 0 : KSTR * l4.y + x4.y;
        k[2] = (l4.z == IGNORE_LB) ? 0 : KSTR * l4.z + x4.z;
        k[3] = (l4.w == IGNORE_LB) ? 0 : KSTR * l4.w + x4.w;
        ushort4 o;
        o.x = (unsigned short)k[0]; o.y = (unsigned short)k[1];
        o.z = (unsigned short)k[2]; o.w = (unsigned short)k[3];
        *(ushort4*)(kb + 4 * i) = o;
        #pragma unroll
        for (int j = 0; j < 4; ++j) atomicAdd(&hist[k[j]], 1u);
    }
    __syncthreads();
    for (int i = threadIdx.x; i < NSEG; i += blockDim.x)
        if (hist[i]) atomicAdd(&counts[b * NSEG + i], hist[i]);
}

// exclusive prefix sum of counts -> cursor. One wave per batch.
__global__ void k_scan(const unsigned int* __restrict__ counts,
                       unsigned int* __restrict__ cursor) {
    const int b = threadIdx.x >> 6, lane = threadIdx.x & 63;
    if (b >= BATCH) return;
    unsigned int carry = 0u;
    for (int c = 0; c < (NSEG + 63) / 64; ++c) {
        const int s = c * 64 + lane;
        unsigned int v0 = (s < NSEG) ? counts[b * NSEG + s] : 0u;
        unsigned int v = v0;
        #pragma unroll
        for (int o = 1; o < 64; o <<= 1) {
            unsigned int t = __shfl_up(v, o, 64);
            if (lane >= o) v += t;
        }
        if (s < NSEG) cursor[b * NSEG + s] = carry + (v - v0);
        carry += __shfl(v, 63, 64);
    }
}

// assign each pixel its sorted position (order within a key irrelevant)
__global__ void k_scatter(const unsigned short* __restrict__ keys,
                          unsigned int* __restrict__ cursor,
                          unsigned int* __restrict__ posOf,
                          unsigned short* __restrict__ skey) {
    const int b = blockIdx.y;
    const int base = blockIdx.x * 2048;
    const unsigned short* kb = keys + (size_t)b * PIX;
    unsigned int* po = posOf + (size_t)b * PIX;
    unsigned short* sk = skey + (size_t)b * PIX;
    #pragma unroll
    for (int j = 0; j < 8; ++j) {
        const int p = base + j * 256 + threadIdx.x;
        const int k = kb[p];
        const unsigned int pos = atomicAdd(&cursor[b * NSEG + k], 1u);
        po[p] = pos;
        sk[pos] = (unsigned short)k;
    }
}

// transpose [D][P] -> sorted [pos][D] with f32->bf16, 64x64 tiles via LDS
__global__ __launch_bounds__(256) void k_tpose(const float* __restrict__ feat,
                                               const unsigned int* __restrict__ posOf,
                                               unsigned short* __restrict__ featS) {
    __shared__ unsigned short tile[64][72];   // row stride 144B (16B-aligned), 9.2KB
    __shared__ unsigned int posLDS[64];
    const int b = blockIdx.y;
    const int P0 = blockIdx.x * 64;
    const int tid = threadIdx.x;
    if (tid < 64) posLDS[tid] = posOf[(size_t)b * PIX + P0 + tid];
    const float* fb = feat + (size_t)b * DCH * PIX;
    #pragma unroll
    for (int i = 0; i < 4; ++i) {
        const int idx = i * 256 + tid;
        const int ch = idx >> 4, px4 = idx & 15;
        const float4 v = *(const float4*)(fb + (size_t)ch * PIX + P0 + 4 * px4);
        tile[4 * px4 + 0][ch] = f2bf(v.x);
        tile[4 * px4 + 1][ch] = f2bf(v.y);
        tile[4 * px4 + 2][ch] = f2bf(v.z);
        tile[4 * px4 + 3][ch] = f2bf(v.w);
    }
    __syncthreads();
    unsigned short* fS = featS + (size_t)b * PIX * DCH;
    #pragma unroll
    for (int i = 0; i < 4; ++i) {
        const int idx = i * 256 + tid;
        const int px = idx >> 4, c4 = idx & 15;
        const unsigned int* t32 = (const unsigned int*)&tile[px][4 * c4];
        uint2 w; w.x = t32[0]; w.y = t32[1];
        *(uint2*)(fS + ((size_t)posLDS[px]) * DCH + 4 * c4) = w;
    }
}

// sorted segment sums: lane = channel, register accumulate, flush on key change
__global__ __launch_bounds__(256) void k_segsum(const unsigned short* __restrict__ featS,
                                                const unsigned short* __restrict__ skey,
                                                float* __restrict__ sums) {
    const int b = blockIdx.y;
    const int lane = threadIdx.x & 63, wid = threadIdx.x >> 6;
    const int q0 = (blockIdx.x * 4 + wid) * 64;
    const unsigned short* fS = featS + (size_t)b * PIX * DCH;
    const int sk = skey[(size_t)b * PIX + q0 + lane];
    int cur = __shfl(sk, 0, 64);
    float acc = 0.f;
    #pragma unroll 8
    for (int j = 0; j < 64; ++j) {
        const int k = __shfl(sk, j, 64);
        const unsigned int u = fS[(size_t)(q0 + j) * DCH + lane];
        const float f = __uint_as_float(u << 16);
        if (k != cur) {
            unsafeAtomicAdd(&sums[((size_t)b * NSEG + cur) * DCH + lane], acc);
            acc = 0.f;
            cur = k;
        }
        acc += f;
    }
    unsafeAtomicAdd(&sums[((size_t)b * NSEG + cur) * DCH + lane], acc);
}

// pairwise tile kernel: means on the fly from sums/counts
__global__ void k_pairs(const float* __restrict__ sums,
                        const unsigned int* __restrict__ counts,
                        float* __restrict__ pairsum) {
    __shared__ float rI[TI][DCH + 1], rJ[TI][DCH + 1];
    __shared__ int cI[TI], cJ[TI];
    __shared__ float ps[NCLS * NCLS];
    const int b = blockIdx.z;
    const int i0 = blockIdx.x * TI, j0 = blockIdx.y * TI;
    if (threadIdx.x < NCLS * NCLS) ps[threadIdx.x] = 0.f;
    for (int t = threadIdx.x; t < TI * DCH; t += blockDim.x) {
        const int r = t >> 6, d = t & 63;
        const int si = i0 + r, sj = j0 + r;
        float vi = 0.f, vj = 0.f;
        if (si < NSEG) {
            const float c = fmaxf((float)counts[b * NSEG + si], 1.f);
            vi = sums[((size_t)b * NSEG + si) * DCH + d] / c;
        }
        if (sj < NSEG) {
            const float c = fmaxf((float)counts[b * NSEG + sj], 1.f);
            vj = sums[((size_t)b * NSEG + sj) * DCH + d] / c;
        }
        rI[r][d] = vi;
        rJ[r][d] = vj;
    }
    if (threadIdx.x < TI) {
        int si = i0 + threadIdx.x;
        bool ok = (si > 0 && si < NSEG && counts[b * NSEG + si] >= 2u);
        cI[threadIdx.x] = ok ? (si - 1) / KSTR : -1;
        int sj = j0 + threadIdx.x;
        ok = (sj > 0 && sj < NSEG && counts[b * NSEG + sj] >= 2u);
        cJ[threadIdx.x] = ok ? (sj - 1) / KSTR : -1;
    }
    __syncthreads();
    const int ti = threadIdx.x >> 4, tj = threadIdx.x & 15;
    const int ci = cI[ti], cj = cJ[tj];
    if (ci >= 0 && ci < NCLS && cj >= 0 && cj < NCLS) {
        float s = 0.f;
        #pragma unroll
        for (int d = 0; d < DCH; ++d) s += fabsf(rI[ti][d] - rJ[tj][d]);
        unsafeAtomicAdd(&ps[ci * NCLS + cj], s * (1.f / DCH));
    }
    __syncthreads();
    if (threadIdx.x < NCLS * NCLS && ps[threadIdx.x] != 0.f)
        unsafeAtomicAdd(&pairsum[b * NCLS * NCLS + threadIdx.x], ps[threadIdx.x]);
}

__global__ void k_final(const unsigned int* __restrict__ counts,
                        const float* __restrict__ pairsum,
                        float* __restrict__ out) {
    __shared__ int nc[BATCH][NCLS];
    __shared__ float psl[BATCH * NCLS * NCLS];
    const int tid = threadIdx.x;
    if (tid < BATCH * NCLS) nc[tid / NCLS][tid % NCLS] = 0;
    if (tid < BATCH * NCLS * NCLS) psl[tid] = pairsum[tid];
    __syncthreads();
    for (int t = tid; t < BATCH * NSEG; t += blockDim.x) {
        const int b = t / NSEG, s = t % NSEG;
        if (s > 0 && counts[t] >= 2u) {
            const int c = (s - 1) / KSTR;
            if (c >= 0 && c < NCLS) atomicAdd(&nc[b][c], 1);
        }
    }
    __syncthreads();
    if (tid == 0) {
        float tot_s = 0.f, tot_c = 0.f;
        for (int b = 0; b < BATCH; ++b)
            for (int c1 = 0; c1 < NCLS; ++c1)
                for (int c2 = c1 + 1; c2 < NCLS; ++c2) {
                    const float np = (float)nc[b][c1] * (float)nc[b][c2];
                    if (np > 0.f) {
                        const float r = psl[b * NCLS * NCLS + c1 * NCLS + c2] / np;
                        tot_s += (r < 1.f) ? 0.5f * r * r : r - 0.5f;
                        tot_c += 1.f;
                    }
                }
        float mh = tot_s / fmaxf(tot_c, 1.f);
        mh = fmaxf(mh, 1e-12f);
        out[0] = (tot_c > 0.f) ? -logf(mh / (float)BATCH) : 0.f;
    }
}

extern "C" void kernel_launch(void* const* d_in, const int* in_sizes, int n_in,
                              void* d_out, int out_size, void* d_ws, size_t ws_size,
                              hipStream_t stream) {
    const float* feat = (const float*)d_in[0];
    const int* lab = (const int*)d_in[1];
    const int* idx = (const int*)d_in[2];
    float* out = (float*)d_out;
    char* ws = (char*)d_ws;

    float* pairsum       = (float*)(ws + OFF_PAIR);
    unsigned int* counts = (unsigned int*)(ws + OFF_CNT);
    float* sums          = (float*)(ws + OFF_SUM);
    unsigned int* cursor = (unsigned int*)(ws + OFF_CUR);
    unsigned short* keys = (unsigned short*)(ws + OFF_KEYS);
    unsigned short* skey = (unsigned short*)(ws + OFF_SKEY);
    unsigned int* posOf  = (unsigned int*)(ws + OFF_POS);
    unsigned short* featS= (unsigned short*)(ws + OFF_FEATS);

    k_zero<<<82, 256, 0, stream>>>((float4*)ws);
    k_keys<<<dim3(64, BATCH), 256, 0, stream>>>(lab, idx, keys, counts);
    k_scan<<<1, 128, 0, stream>>>(counts, cursor);
    k_scatter<<<dim3(PIX / 2048, BATCH), 256, 0, stream>>>(keys, cursor, posOf, skey);
    k_tpose<<<dim3(PIX / 64, BATCH), 256, 0, stream>>>(feat, posOf, featS);
    k_segsum<<<dim3(PIX / 256, BATCH), 256, 0, stream>>>(featS, skey, sums);
    k_pairs<<<dim3((NSEG + TI - 1) / TI, (NSEG + TI - 1) / TI, BATCH), 256, 0, stream>>>(
        sums, counts, pairsum);
    k_final<<<1, 256, 0, stream>>>(counts, pairsum, out);
}

// Round 7
// 114.897 us; speedup vs baseline: 2.0583x; 1.5261x over previous
//
#include <hip/hip_runtime.h>
#include <math.h>

#define BATCH 2
#define DCH 64
#define PIX (512 * 512)
#define NCLS 5
#define IGNORE_LB 255
#define KSTR 129                      // fixed injective key stride (> MAX_INDEX)
#define NSEG 645                      // KSTR*4 + 128 + 1
#define NBLK 64                       // key/scatter blocks per batch (4096 px each)
#define TI 16                         // pair-tile edge

// ---- workspace layout (bytes) ----
// zero region (zeroed by k_zero each call):
#define OFF_PAIR  0                                    // float pairsum[BATCH][25]
#define OFF_SUM   256                                  // float sums[BATCH][NSEG][DCH]
#define ZERO_BYTES 330496                              // 256 + 330240, mult of 16
// non-zeroed (fully rewritten each call):
#define OFF_CNT   330496                               // uint counts[BATCH][NSEG]
#define OFF_BASE  335872                               // uint base[BATCH][NSEG]
#define OFF_BHIST 341248                               // uint blockHist[BATCH][NBLK][NSEG]
#define OFF_KEYS  671488                               // ushort keys[BATCH][PIX]
#define OFF_SKEY  1720064                              // ushort skey[BATCH][PIX]
#define OFF_POS   2768640                               // uint posOf[BATCH][PIX]
#define OFF_FEATS 4865792                              // ushort(bf16) featS[BATCH][PIX][DCH]

__global__ void k_zero(float4* __restrict__ p) {
    const int n4 = ZERO_BYTES / 16;
    for (int i = blockIdx.x * blockDim.x + threadIdx.x; i < n4;
         i += gridDim.x * blockDim.x)
        p[i] = make_float4(0.f, 0.f, 0.f, 0.f);
}

__device__ __forceinline__ unsigned short f2bf(float f) {   // round-to-nearest-even
    unsigned int u = __float_as_uint(f);
    u += 0x7FFFu + ((u >> 16) & 1u);
    return (unsigned short)(u >> 16);
}

// contiguous 4096-px chunk per block; per-block histogram dumped non-atomically
__global__ void k_keys(const int* __restrict__ lab, const int* __restrict__ idx,
                       unsigned short* __restrict__ keys,
                       unsigned int* __restrict__ blockHist) {
    __shared__ unsigned int hist[NSEG];
    const int b = blockIdx.y, blk = blockIdx.x;
    for (int i = threadIdx.x; i < NSEG; i += blockDim.x) hist[i] = 0u;
    __syncthreads();
    const int4* lb = (const int4*)(lab + (size_t)b * PIX);
    const int4* ib = (const int4*)(idx + (size_t)b * PIX);
    unsigned short* kb = keys + (size_t)b * PIX;
    #pragma unroll
    for (int it = 0; it < 4; ++it) {
        const int g = blk * 1024 + it * 256 + threadIdx.x;   // int4 group
        const int4 l4 = lb[g];
        const int4 x4 = ib[g];
        int k[4];
        k[0] = (l4.x == IGNORE_LB) ? 0 : KSTR * l4.x + x4.x;
        k[1] = (l4.y == IGNORE_LB) ? 0 : KSTR * l4.y + x4.y;
        k[2] = (l4.z == IGNORE_LB) ? 0 : KSTR * l4.z + x4.z;
        k[3] = (l4.w == IGNORE_LB) ? 0 : KSTR * l4.w + x4.w;
        ushort4 o;
        o.x = (unsigned short)k[0]; o.y = (unsigned short)k[1];
        o.z = (unsigned short)k[2]; o.w = (unsigned short)k[3];
        *(ushort4*)(kb + 4 * g) = o;
        #pragma unroll
        for (int j = 0; j < 4; ++j) atomicAdd(&hist[k[j]], 1u);
    }
    __syncthreads();
    unsigned int* bh = blockHist + ((size_t)b * NBLK + blk) * NSEG;
    for (int i = threadIdx.x; i < NSEG; i += blockDim.x) bh[i] = hist[i];
}

// per batch: column-sum blockHist -> counts; blockHist -> per-block exclusive
// prefix (in place); wave-scan totals -> base[s]
__global__ void k_scan(unsigned int* __restrict__ blockHist,
                       unsigned int* __restrict__ counts,
                       unsigned int* __restrict__ base) {
    __shared__ unsigned int tot[NSEG];
    const int b = blockIdx.x;
    unsigned int* bh = blockHist + (size_t)b * NBLK * NSEG;
    for (int s = threadIdx.x; s < NSEG; s += blockDim.x) {
        unsigned int run = 0u;
        #pragma unroll 8
        for (int blk = 0; blk < NBLK; ++blk) {
            const unsigned int t = bh[(size_t)blk * NSEG + s];
            bh[(size_t)blk * NSEG + s] = run;
            run += t;
        }
        tot[s] = run;
        counts[b * NSEG + s] = run;
    }
    __syncthreads();
    if (threadIdx.x < 64) {
        const int lane = threadIdx.x;
        unsigned int carry = 0u;
        for (int c = 0; c < (NSEG + 63) / 64; ++c) {
            const int s = c * 64 + lane;
            unsigned int v0 = (s < NSEG) ? tot[s] : 0u;
            unsigned int v = v0;
            #pragma unroll
            for (int o = 1; o < 64; o <<= 1) {
                unsigned int t = __shfl_up(v, o, 64);
                if (lane >= o) v += t;
            }
            if (s < NSEG) base[b * NSEG + s] = carry + (v - v0);
            carry += __shfl(v, 63, 64);
        }
    }
}

// positions via LDS cursor seeded from base + per-block offset; no global atomics
__global__ void k_scatter(const unsigned short* __restrict__ keys,
                          const unsigned int* __restrict__ blockHist,
                          const unsigned int* __restrict__ base,
                          unsigned int* __restrict__ posOf,
                          unsigned short* __restrict__ skey) {
    __shared__ unsigned int cur[NSEG];
    const int b = blockIdx.y, blk = blockIdx.x;
    const unsigned int* bh = blockHist + ((size_t)b * NBLK + blk) * NSEG;
    for (int s = threadIdx.x; s < NSEG; s += blockDim.x)
        cur[s] = base[b * NSEG + s] + bh[s];
    __syncthreads();
    const unsigned short* kb = keys + (size_t)b * PIX;
    unsigned int* po = posOf + (size_t)b * PIX;
    unsigned short* sk = skey + (size_t)b * PIX;
    #pragma unroll
    for (int it = 0; it < 4; ++it) {
        const int g = blk * 1024 + it * 256 + threadIdx.x;
        const ushort4 k4 = *(const ushort4*)(kb + 4 * g);
        const unsigned short kk[4] = {k4.x, k4.y, k4.z, k4.w};
        #pragma unroll
        for (int j = 0; j < 4; ++j) {
            const unsigned int pos = atomicAdd(&cur[kk[j]], 1u);
            po[4 * g + j] = pos;
            sk[pos] = kk[j];
        }
    }
}

// transpose [D][P] -> sorted [pos][D] with f32->bf16, 64x64 tiles via LDS
__global__ __launch_bounds__(256) void k_tpose(const float* __restrict__ feat,
                                               const unsigned int* __restrict__ posOf,
                                               unsigned short* __restrict__ featS) {
    __shared__ unsigned short tile[64][72];   // row stride 144B (16B-aligned), 9.2KB
    __shared__ unsigned int posLDS[64];
    const int b = blockIdx.y;
    const int P0 = blockIdx.x * 64;
    const int tid = threadIdx.x;
    if (tid < 64) posLDS[tid] = posOf[(size_t)b * PIX + P0 + tid];
    const float* fb = feat + (size_t)b * DCH * PIX;
    #pragma unroll
    for (int i = 0; i < 4; ++i) {
        const int idx = i * 256 + tid;
        const int ch = idx >> 4, px4 = idx & 15;
        const float4 v = *(const float4*)(fb + (size_t)ch * PIX + P0 + 4 * px4);
        tile[4 * px4 + 0][ch] = f2bf(v.x);
        tile[4 * px4 + 1][ch] = f2bf(v.y);
        tile[4 * px4 + 2][ch] = f2bf(v.z);
        tile[4 * px4 + 3][ch] = f2bf(v.w);
    }
    __syncthreads();
    unsigned short* fS = featS + (size_t)b * PIX * DCH;
    #pragma unroll
    for (int i = 0; i < 4; ++i) {
        const int idx = i * 256 + tid;
        const int px = idx >> 4, c4 = idx & 15;
        const unsigned int* t32 = (const unsigned int*)&tile[px][4 * c4];
        uint2 w; w.x = t32[0]; w.y = t32[1];
        *(uint2*)(fS + ((size_t)posLDS[px]) * DCH + 4 * c4) = w;
    }
}

// sorted segment sums: lane = channel, register accumulate, flush on key change
__global__ __launch_bounds__(256) void k_segsum(const unsigned short* __restrict__ featS,
                                                const unsigned short* __restrict__ skey,
                                                float* __restrict__ sums) {
    const int b = blockIdx.y;
    const int lane = threadIdx.x & 63, wid = threadIdx.x >> 6;
    const int q0 = (blockIdx.x * 4 + wid) * 64;
    const unsigned short* fS = featS + (size_t)b * PIX * DCH;
    const int sk = skey[(size_t)b * PIX + q0 + lane];
    int cur = __shfl(sk, 0, 64);
    float acc = 0.f;
    #pragma unroll 8
    for (int j = 0; j < 64; ++j) {
        const int k = __shfl(sk, j, 64);
        const unsigned int u = fS[(size_t)(q0 + j) * DCH + lane];
        const float f = __uint_as_float(u << 16);
        if (k != cur) {
            unsafeAtomicAdd(&sums[((size_t)b * NSEG + cur) * DCH + lane], acc);
            acc = 0.f;
            cur = k;
        }
        acc += f;
    }
    unsafeAtomicAdd(&sums[((size_t)b * NSEG + cur) * DCH + lane], acc);
}

// pairwise tile kernel: means on the fly from sums/counts
__global__ void k_pairs(const float* __restrict__ sums,
                        const unsigned int* __restrict__ counts,
                        float* __restrict__ pairsum) {
    __shared__ float rI[TI][DCH + 1], rJ[TI][DCH + 1];
    __shared__ int cI[TI], cJ[TI];
    __shared__ float ps[NCLS * NCLS];
    const int b = blockIdx.z;
    const int i0 = blockIdx.x * TI, j0 = blockIdx.y * TI;
    if (threadIdx.x < NCLS * NCLS) ps[threadIdx.x] = 0.f;
    for (int t = threadIdx.x; t < TI * DCH; t += blockDim.x) {
        const int r = t >> 6, d = t & 63;
        const int si = i0 + r, sj = j0 + r;
        float vi = 0.f, vj = 0.f;
        if (si < NSEG) {
            const float c = fmaxf((float)counts[b * NSEG + si], 1.f);
            vi = sums[((size_t)b * NSEG + si) * DCH + d] / c;
        }
        if (sj < NSEG) {
            const float c = fmaxf((float)counts[b * NSEG + sj], 1.f);
            vj = sums[((size_t)b * NSEG + sj) * DCH + d] / c;
        }
        rI[r][d] = vi;
        rJ[r][d] = vj;
    }
    if (threadIdx.x < TI) {
        int si = i0 + threadIdx.x;
        bool ok = (si > 0 && si < NSEG && counts[b * NSEG + si] >= 2u);
        cI[threadIdx.x] = ok ? (si - 1) / KSTR : -1;
        int sj = j0 + threadIdx.x;
        ok = (sj > 0 && sj < NSEG && counts[b * NSEG + sj] >= 2u);
        cJ[threadIdx.x] = ok ? (sj - 1) / KSTR : -1;
    }
    __syncthreads();
    const int ti = threadIdx.x >> 4, tj = threadIdx.x & 15;
    const int ci = cI[ti], cj = cJ[tj];
    if (ci >= 0 && ci < NCLS && cj >= 0 && cj < NCLS) {
        float s = 0.f;
        #pragma unroll
        for (int d = 0; d < DCH; ++d) s += fabsf(rI[ti][d] - rJ[tj][d]);
        unsafeAtomicAdd(&ps[ci * NCLS + cj], s * (1.f / DCH));
    }
    __syncthreads();
    if (threadIdx.x < NCLS * NCLS && ps[threadIdx.x] != 0.f)
        unsafeAtomicAdd(&pairsum[b * NCLS * NCLS + threadIdx.x], ps[threadIdx.x]);
}

__global__ void k_final(const unsigned int* __restrict__ counts,
                        const float* __restrict__ pairsum,
                        float* __restrict__ out) {
    __shared__ int nc[BATCH][NCLS];
    __shared__ float psl[BATCH * NCLS * NCLS];
    const int tid = threadIdx.x;
    if (tid < BATCH * NCLS) nc[tid / NCLS][tid % NCLS] = 0;
    if (tid < BATCH * NCLS * NCLS) psl[tid] = pairsum[tid];
    __syncthreads();
    for (int t = tid; t < BATCH * NSEG; t += blockDim.x) {
        const int b = t / NSEG, s = t % NSEG;
        if (s > 0 && counts[t] >= 2u) {
            const int c = (s - 1) / KSTR;
            if (c >= 0 && c < NCLS) atomicAdd(&nc[b][c], 1);
        }
    }
    __syncthreads();
    if (tid == 0) {
        float tot_s = 0.f, tot_c = 0.f;
        for (int b = 0; b < BATCH; ++b)
            for (int c1 = 0; c1 < NCLS; ++c1)
                for (int c2 = c1 + 1; c2 < NCLS; ++c2) {
                    const float np = (float)nc[b][c1] * (float)nc[b][c2];
                    if (np > 0.f) {
                        const float r = psl[b * NCLS * NCLS + c1 * NCLS + c2] / np;
                        tot_s += (r < 1.f) ? 0.5f * r * r : r - 0.5f;
                        tot_c += 1.f;
                    }
                }
        float mh = tot_s / fmaxf(tot_c, 1.f);
        mh = fmaxf(mh, 1e-12f);
        out[0] = (tot_c > 0.f) ? -logf(mh / (float)BATCH) : 0.f;
    }
}

extern "C" void kernel_launch(void* const* d_in, const int* in_sizes, int n_in,
                              void* d_out, int out_size, void* d_ws, size_t ws_size,
                              hipStream_t stream) {
    const float* feat = (const float*)d_in[0];
    const int* lab = (const int*)d_in[1];
    const int* idx = (const int*)d_in[2];
    float* out = (float*)d_out;
    char* ws = (char*)d_ws;

    float* pairsum        = (float*)(ws + OFF_PAIR);
    float* sums           = (float*)(ws + OFF_SUM);
    unsigned int* counts  = (unsigned int*)(ws + OFF_CNT);
    unsigned int* base    = (unsigned int*)(ws + OFF_BASE);
    unsigned int* bhist   = (unsigned int*)(ws + OFF_BHIST);
    unsigned short* keys  = (unsigned short*)(ws + OFF_KEYS);
    unsigned short* skey  = (unsigned short*)(ws + OFF_SKEY);
    unsigned int* posOf   = (unsigned int*)(ws + OFF_POS);
    unsigned short* featS = (unsigned short*)(ws + OFF_FEATS);

    k_zero<<<81, 256, 0, stream>>>((float4*)ws);
    k_keys<<<dim3(NBLK, BATCH), 256, 0, stream>>>(lab, idx, keys, bhist);
    k_scan<<<BATCH, 256, 0, stream>>>(bhist, counts, base);
    k_scatter<<<dim3(NBLK, BATCH), 256, 0, stream>>>(keys, bhist, base, posOf, skey);
    k_tpose<<<dim3(PIX / 64, BATCH), 256, 0, stream>>>(feat, posOf, featS);
    k_segsum<<<dim3(PIX / 256, BATCH), 256, 0, stream>>>(featS, skey, sums);
    k_pairs<<<dim3((NSEG + TI - 1) / TI, (NSEG + TI - 1) / TI, BATCH), 256, 0, stream>>>(
        sums, counts, pairsum);
    k_final<<<1, 256, 0, stream>>>(counts, pairsum, out);
}